// Round 21
// baseline (108.499 us; speedup 1.0000x reference)
//
#include <hip/hip_runtime.h>
#include <hip/hip_fp8.h>

#define C_ 512
#define T_ 2048
#define N_TOK 16384
#define K_CB 4096

typedef __attribute__((ext_vector_type(16))) float f32x16;
typedef __attribute__((ext_vector_type(2))) long long2v;

static __device__ __forceinline__ unsigned char f2fp8(float f) {
    __hip_fp8_e4m3 v(f);                 // OCP e4m3, RNE + saturate
    return (unsigned char)v.__x;
}

static __device__ __forceinline__ float fsqrt(float x) {
#if __has_builtin(__builtin_amdgcn_sqrtf)
    return __builtin_amdgcn_sqrtf(x);    // raw v_sqrt_f32 (1-2 ulp), no Newton fixup
#else
    float r; asm volatile("v_sqrt_f32 %0, %1" : "=v"(r) : "v"(x)); return r;
#endif
}

typedef const __attribute__((address_space(1))) void* gas_t;
typedef __attribute__((address_space(3))) void* las_t;
static __device__ __forceinline__ void stage16(const void* g, void* l) {
    __builtin_amdgcn_global_load_lds((gas_t)g, (las_t)l, 16, 0, 0);
}

// ---------------- Kernel 1 (merged): blocks 0-511 = student transpose/stats; 512-1535 = codebook
__global__ __launch_bounds__(256) void k1_all(
    const float* __restrict__ student,   // (B,C,T) fp32
    const int* __restrict__ codes,       // (B,T) int32
    const float* __restrict__ codebook,  // (K,C) fp32
    unsigned char* __restrict__ A8,      // (N,C) fp8 out
    unsigned char* __restrict__ B8f,     // fragment-linear fp8 codebook out
    float* __restrict__ cbnorm,
    float* __restrict__ xnorm, float* __restrict__ dtg2)
{
    int tid = threadIdx.x;
    if (blockIdx.x >= 512) {
        // ---------------- codebook -> fragment-linear fp8 + row norms ----------------
        int lane = tid & 63;
        int w = tid >> 6;
        int row = (blockIdx.x - 512) * 4 + w;
        const float* src = codebook + (size_t)row * C_ + lane * 8;
        float4 v0 = *(const float4*)(src);
        float4 v1 = *(const float4*)(src + 4);
        float s = v0.x*v0.x + v0.y*v0.y + v0.z*v0.z + v0.w*v0.w
                + v1.x*v1.x + v1.y*v1.y + v1.z*v1.z + v1.w*v1.w;
        unsigned lo = (unsigned)f2fp8(v0.x) | ((unsigned)f2fp8(v0.y) << 8)
                    | ((unsigned)f2fp8(v0.z) << 16) | ((unsigned)f2fp8(v0.w) << 24);
        unsigned hi = (unsigned)f2fp8(v1.x) | ((unsigned)f2fp8(v1.y) << 8)
                    | ((unsigned)f2fp8(v1.z) << 16) | ((unsigned)f2fp8(v1.w) << 24);
        size_t off = (size_t)(row >> 5) * 16384 + (size_t)(lane >> 1) * 512
                   + (size_t)(lane & 1) * 256 + (size_t)(row & 31) * 8;
        *(uint2*)(B8f + off) = make_uint2(lo, hi);
#pragma unroll
        for (int m = 1; m < 64; m <<= 1) s += __shfl_xor(s, m);
        if (lane == 0) cbnorm[row] = s;
        return;
    }
    // ---------------- student transpose (B,C,T)->(N,C) fp8 + per-token partial stats ----------
    __shared__ float tile[64][65];
    __shared__ int lcodes[64];
    int tnum  = blockIdx.x >> 1;
    int chalf = blockIdx.x & 1;
    int b  = tnum >> 5;
    int t0 = (tnum & 31) << 6;
    int cbase = chalf << 8;             // 0 or 256
    int cx = tid & 63;                  // lane
    int q  = tid >> 6;                  // wave
    if (tid < 64) lcodes[tid] = codes[b * T_ + t0 + tid];
    __syncthreads();
    float ax2[16], ad2[16];
#pragma unroll
    for (int p = 0; p < 16; ++p) { ax2[p] = 0.f; ad2[p] = 0.f; }
    for (int c0 = cbase; c0 < cbase + 256; c0 += 64) {
        // vectorized tile fill: wave q covers channels [q*16, q*16+16), float4 along T
#pragma unroll
        for (int i = 0; i < 4; ++i) {
            int ch = q * 16 + i * 4 + (cx >> 4);
            int tq = cx & 15;
            float4 v = *(const float4*)(student + (size_t)b * (C_ * T_)
                                        + (size_t)(c0 + ch) * T_ + t0 + tq * 4);
            tile[ch][tq * 4 + 0] = v.x;
            tile[ch][tq * 4 + 1] = v.y;
            tile[ch][tq * 4 + 2] = v.z;
            tile[ch][tq * 4 + 3] = v.w;
        }
        __syncthreads();
#pragma unroll
        for (int p = 0; p < 16; ++p) {
            int ty = p * 4 + q;
            float x = tile[cx][ty];
            int n = b * T_ + t0 + ty;
            A8[(size_t)n * C_ + c0 + cx] = f2fp8(x);
            ax2[p] += x * x;
            float cb = codebook[(size_t)lcodes[ty] * C_ + c0 + cx];
            float d = x - cb;
            ad2[p] += d * d;
        }
        __syncthreads();
    }
#pragma unroll
    for (int p = 0; p < 16; ++p) {
        float sx = ax2[p], sd = ad2[p];
#pragma unroll
        for (int m = 1; m < 64; m <<= 1) {
            sx += __shfl_xor(sx, m);
            sd += __shfl_xor(sd, m);
        }
        if (cx == 0) {
            int n = b * T_ + t0 + p * 4 + q;
            atomicAdd(&xnorm[n], sx);
            atomicAdd(&dtg2[n], sd);
        }
    }
}

// ---------------- Kernel 2: R16/R20 base + 4 independent MFMA chains (m-parity split) ----------
// grid = 1024 (256 row-strips x 4 col-quarters, XCD-chunked); block = 512 (8 waves, 1x8).
// acc split by m-parity: bE (even m) -> acc0a/acc1a, bO (odd m) -> acc0b/acc1b. Each chain
// receives ONE MFMA per j-iteration -> same-chain dep distance = 4 MFMAs + loads, covering
// MFMA result latency. Exact math: dot = a + b, merged via one extra fma in the epilogue.
// +32 AGPR (total ~104 unified, under the (512,4) cap -- not the R17/18/19 spill shape).
__global__ __launch_bounds__(512, 4) void k2_main(
    const unsigned char* __restrict__ A8,
    const unsigned char* __restrict__ B8f,
    const float* __restrict__ xnorm,
    const float* __restrict__ dtg2,
    const float* __restrict__ cbnorm,
    float* __restrict__ s_sum,
    unsigned* __restrict__ minpack)
{
    __shared__ __align__(16) unsigned char aL[32768];      // A: [rt2][j16][lane64][16B]
    __shared__ __align__(16) float cbL[1024];              // cbnorm for this col-quarter
    int tid = threadIdx.x;
    int lane = tid & 63;
    int wc = tid >> 6;                   // 0..7: wave owns cols [wc*32, wc*32+32) of each cc
    int l31 = lane & 31;
    int kh = lane >> 5;

    int orig = blockIdx.x;               // 1024 = 8 XCD x 128
    int swz = (orig & 7) * 128 + (orig >> 3);
    int strip = swz >> 2;                // 0..255
    int cq = swz & 3;                    // col quarter 0..3
    int row0 = strip * 64;
    int cbase = cq * 1024;

    // ---- stage A once, reg->LDS, m-pair fragment-linear layout (R14-verified) ----
#pragma unroll
    for (int i = 0; i < 4; ++i) {
        int li = i * 512 + tid;
        int R = li >> 5, M = li & 31;
        uint4 v = *(const uint4*)(A8 + (size_t)(row0 + R) * C_ + M * 16);
        char* base = (char*)aL + (R >> 5) * 16384 + (M >> 1) * 1024 + (M & 1) * 8;
        *(uint2*)(base + (R & 31) * 16)       = make_uint2(v.x, v.y);   // kh = 0
        *(uint2*)(base + 512 + (R & 31) * 16) = make_uint2(v.z, v.w);   // kh = 1
    }
    // ---- stage cbnorm quarter once ----
    if (tid < 256)
        stage16((const char*)cbnorm + (size_t)cbase * 4 + tid * 16, (char*)cbL + tid * 16);
    __syncthreads();                     // the ONLY barrier

    int myrow0 = row0 + l31, myrow1 = row0 + 32 + l31;
    float xn0 = xnorm[myrow0], xn1 = xnorm[myrow1];
    float dt0 = fsqrt(dtg2[myrow0]), dt1 = fsqrt(dtg2[myrow1]);
    float sv0 = 0.f, sv1 = 0.f;
    unsigned km0 = 0xFFFFFFFFu, km1 = 0xFFFFFFFFu;

    f32x16 acc0a, acc0b, acc1a, acc1b;   // 4 independent chains (m-parity x rt)
#pragma unroll
    for (int r = 0; r < 16; ++r) { acc0a[r]=0.f; acc0b[r]=0.f; acc1a[r]=0.f; acc1b[r]=0.f; }

    const char* aBase = (const char*)aL + lane * 16;   // single LDS addr reg; imm offsets
    unsigned sOff = (unsigned)__builtin_amdgcn_readfirstlane((cq * 32 + wc) * 16384);
    const unsigned char* gB = B8f + sOff + lane * 8;
    int wlc = wc * 32 + 4 * kh;          // lane's col base within a cc (local)
    const float NL2E = -1.44269504f;     // -log2(e)

    for (int cc = 0; cc < 4; ++cc) {
#pragma unroll 4
        for (int j = 0; j < 16; ++j) {
            long bE = *(const long*)(gB + j * 1024);          // B frag m=2j   (even)
            long bO = *(const long*)(gB + j * 1024 + 512);    // B frag m=2j+1 (odd)
            long2v a0 = *(const long2v*)(aBase + j * 1024);           // rt0: {m=2j, m=2j+1}
            long2v a1 = *(const long2v*)(aBase + 16384 + j * 1024);   // rt1
            acc0a = __builtin_amdgcn_mfma_f32_32x32x16_fp8_fp8(bE, a0[0], acc0a, 0, 0, 0);
            acc1a = __builtin_amdgcn_mfma_f32_32x32x16_fp8_fp8(bE, a1[0], acc1a, 0, 0, 0);
            acc0b = __builtin_amdgcn_mfma_f32_32x32x16_fp8_fp8(bO, a0[1], acc0b, 0, 0, 0);
            acc1b = __builtin_amdgcn_mfma_f32_32x32x16_fp8_fp8(bO, a1[1], acc1b, 0, 0, 0);
        }
        gB += 8 * 16384;                 // uniform bump (SALU)
        // ---- epilogue burst: merge parity chains via extra fma; folded exp; d2-key argmin ----
        int lc0 = cc * 256 + wlc;
#pragma unroll
        for (int r = 0; r < 16; ++r) {
            int lc = lc0 + (r & 3) + 8 * (r >> 2);
            float cbn = cbL[lc];
            float d2a = fmaxf(fmaf(-2.f, acc0b[r], fmaf(-2.f, acc0a[r], xn0 + cbn)), 0.f);
            sv0 += exp2f(fsqrt(d2a) * NL2E);
            km0 = min(km0, (__float_as_uint(d2a) & 0xFFFFF000u) | (unsigned)(cbase + lc));
            float d2b = fmaxf(fmaf(-2.f, acc1b[r], fmaf(-2.f, acc1a[r], xn1 + cbn)), 0.f);
            sv1 += exp2f(fsqrt(d2b) * NL2E);
            km1 = min(km1, (__float_as_uint(d2b) & 0xFFFFF000u) | (unsigned)(cbase + lc));
            acc0a[r] = 0.f; acc0b[r] = 0.f; acc1a[r] = 0.f; acc1b[r] = 0.f;
        }
    }

    // merge k-halves (lane vs lane+32: same student rows, disjoint cb-col quads)
    sv0 += __shfl_xor(sv0, 32);
    sv1 += __shfl_xor(sv1, 32);
    km0 = min(km0, (unsigned)__shfl_xor((int)km0, 32));
    km1 = min(km1, (unsigned)__shfl_xor((int)km1, 32));
    if (lane < 32) {
        atomicAdd(&s_sum[myrow0], sv0 * __expf(dt0));   // e^dt * sum(e^-d) = sum(e^(dt-d))
        atomicMin(&minpack[myrow0], km0);
        atomicAdd(&s_sum[myrow1], sv1 * __expf(dt1));
        atomicMin(&minpack[myrow1], km1);
    }
}

// ---------------- Kernel 3a: per-token CE/accuracy/emb-loss/target-dist reduce ----------------
__global__ __launch_bounds__(256) void k3a(
    const float* __restrict__ s_sum,
    const unsigned* __restrict__ minpack,
    const int* __restrict__ codes,
    const float* __restrict__ dtg2,
    float* __restrict__ accum)
{
    __shared__ float w0[4], w1[4], w2[4], w3[4];
    int tid = threadIdx.x;
    int n = blockIdx.x * 256 + tid;
    float ce = logf(s_sum[n]);           // = d_t + lse(-d) = per-token CE
    unsigned pred = minpack[n] & 0xFFFu; // col id in the low 12 bits
    float ok = (pred == (unsigned)codes[n]) ? 1.f : 0.f;
    float sq = dtg2[n];
    float td = sqrtf(sq);
#pragma unroll
    for (int m = 1; m < 64; m <<= 1) {
        ce += __shfl_xor(ce, m);
        ok += __shfl_xor(ok, m);
        sq += __shfl_xor(sq, m);
        td += __shfl_xor(td, m);
    }
    int lane = tid & 63, w = tid >> 6;
    if (lane == 0) { w0[w] = ce; w1[w] = ok; w2[w] = sq; w3[w] = td; }
    __syncthreads();
    if (tid == 0) {
        atomicAdd(&accum[0], w0[0] + w0[1] + w0[2] + w0[3]);
        atomicAdd(&accum[1], w1[0] + w1[1] + w1[2] + w1[3]);
        atomicAdd(&accum[2], w2[0] + w2[1] + w2[2] + w2[3]);
        atomicAdd(&accum[3], w3[0] + w3[1] + w3[2] + w3[3]);
    }
}

// ---------------- Kernel 3b: finalize 5 outputs ----------------
__global__ void k3b(const float* __restrict__ accum, float* __restrict__ out)
{
    if (threadIdx.x == 0 && blockIdx.x == 0) {
        float ce   = accum[0] / (float)N_TOK;
        float accy = accum[1] / (float)N_TOK;
        float emb  = accum[2] / ((float)N_TOK * (float)C_);
        float td   = accum[3] / (float)N_TOK;
        out[0] = emb + ce;   // total_loss (EMB_W=CE_W=1)
        out[1] = emb;        // emb_to_codebook_loss
        out[2] = ce;         // ce_loss
        out[3] = accy;       // token_accuracy
        out[4] = td;         // emb_to_target_dist
    }
}

extern "C" void kernel_launch(void* const* d_in, const int* in_sizes, int n_in,
                              void* d_out, int out_size, void* d_ws, size_t ws_size,
                              hipStream_t stream)
{
    const float* student  = (const float*)d_in[0];
    const int*   codes    = (const int*)d_in[1];
    const float* codebook = (const float*)d_in[2];
    // d_in[3] distance_matrix is unused by the reference.
    float* out = (float*)d_out;

    char* ws = (char*)d_ws;
    unsigned char* A8     = (unsigned char*)(ws);                  // 8 MiB
    unsigned char* B8f    = (unsigned char*)(ws + 8388608);        // 2 MiB (fragment-linear)
    float* xnorm          = (float*)(ws + 10485760);               // 64 KiB  ─┐
    float* dtg2           = (float*)(ws + 10551296);               // 64 KiB   │ one zero-memset
    float* s_sum          = (float*)(ws + 10616832);               // 64 KiB   │
    float* accum          = (float*)(ws + 10682368);               // 64 B    ─┘
    unsigned* minpack     = (unsigned*)(ws + 10682624);            // 64 KiB (0xFF memset)
    float* cbnorm         = (float*)(ws + 10748160);               // 16 KiB (fully written by k1)

    hipMemsetAsync(ws + 10485760, 0, 196672, stream);              // xnorm+dtg2+s_sum+accum
    hipMemsetAsync(ws + 10682624, 0xFF, 65536, stream);            // minpack

    // merged prep: blocks 0-511 student transpose/stats, 512-1535 codebook conversion
    hipLaunchKernelGGL(k1_all, dim3(1536), dim3(256), 0, stream,
                       student, codes, codebook, A8, B8f, cbnorm, xnorm, dtg2);
    hipLaunchKernelGGL(k2_main, dim3(1024), dim3(512), 0, stream,
                       A8, B8f, xnorm, dtg2, cbnorm, s_sum, minpack);
    hipLaunchKernelGGL(k3a, dim3(64), dim3(256), 0, stream,
                       s_sum, minpack, codes, dtg2, accum);
    hipLaunchKernelGGL(k3b, dim3(1), dim3(64), 0, stream, accum, out);
}

// Round 22
// 97.237 us; speedup vs baseline: 1.1158x; 1.1158x over previous
//
#include <hip/hip_runtime.h>
#include <hip/hip_fp8.h>

#define C_ 512
#define T_ 2048
#define N_TOK 16384
#define K_CB 4096

typedef __attribute__((ext_vector_type(16))) float f32x16;
typedef __attribute__((ext_vector_type(2))) long long2v;

static __device__ __forceinline__ unsigned char f2fp8(float f) {
    __hip_fp8_e4m3 v(f);                 // OCP e4m3, RNE + saturate
    return (unsigned char)v.__x;
}

static __device__ __forceinline__ float fsqrt(float x) {
#if __has_builtin(__builtin_amdgcn_sqrtf)
    return __builtin_amdgcn_sqrtf(x);    // raw v_sqrt_f32 (1-2 ulp), no Newton fixup
#else
    float r; asm volatile("v_sqrt_f32 %0, %1" : "=v"(r) : "v"(x)); return r;
#endif
}

typedef const __attribute__((address_space(1))) void* gas_t;
typedef __attribute__((address_space(3))) void* las_t;
static __device__ __forceinline__ void stage16(const void* g, void* l) {
    __builtin_amdgcn_global_load_lds((gas_t)g, (las_t)l, 16, 0, 0);
}

// ---------------- Kernel 1 (merged): blocks 0-511 = student transpose/stats; 512-1535 = codebook
// Pass-2 vectorized via token-major tile: per thread 4x{float4 tile read + float4 gather +
// packed dword A8 store} per c-chunk (was 16 scalar gathers + 16 byte stores + 16 scalar reads).
__global__ __launch_bounds__(256) void k1_all(
    const float* __restrict__ student,   // (B,C,T) fp32
    const int* __restrict__ codes,       // (B,T) int32
    const float* __restrict__ codebook,  // (K,C) fp32
    unsigned char* __restrict__ A8,      // (N,C) fp8 out
    unsigned char* __restrict__ B8f,     // fragment-linear fp8 codebook out
    float* __restrict__ cbnorm,
    float* __restrict__ xnorm, float* __restrict__ dtg2)
{
    int tid = threadIdx.x;
    if (blockIdx.x >= 512) {
        // ---------------- codebook -> fragment-linear fp8 + row norms ----------------
        int lane = tid & 63;
        int w = tid >> 6;
        int row = (blockIdx.x - 512) * 4 + w;
        const float* src = codebook + (size_t)row * C_ + lane * 8;
        float4 v0 = *(const float4*)(src);
        float4 v1 = *(const float4*)(src + 4);
        float s = v0.x*v0.x + v0.y*v0.y + v0.z*v0.z + v0.w*v0.w
                + v1.x*v1.x + v1.y*v1.y + v1.z*v1.z + v1.w*v1.w;
        unsigned lo = (unsigned)f2fp8(v0.x) | ((unsigned)f2fp8(v0.y) << 8)
                    | ((unsigned)f2fp8(v0.z) << 16) | ((unsigned)f2fp8(v0.w) << 24);
        unsigned hi = (unsigned)f2fp8(v1.x) | ((unsigned)f2fp8(v1.y) << 8)
                    | ((unsigned)f2fp8(v1.z) << 16) | ((unsigned)f2fp8(v1.w) << 24);
        size_t off = (size_t)(row >> 5) * 16384 + (size_t)(lane >> 1) * 512
                   + (size_t)(lane & 1) * 256 + (size_t)(row & 31) * 8;
        *(uint2*)(B8f + off) = make_uint2(lo, hi);
#pragma unroll
        for (int m = 1; m < 64; m <<= 1) s += __shfl_xor(s, m);
        if (lane == 0) cbnorm[row] = s;
        return;
    }
    // ---------------- student transpose (B,C,T)->(N,C) fp8 + per-token partial stats ----------
    __shared__ float tile[64][68];       // [tok][ch]: float4-aligned (272B rows), 2-way reads
    __shared__ int lcodes[64];
    int tnum  = blockIdx.x >> 1;
    int chalf = blockIdx.x & 1;
    int b  = tnum >> 5;
    int t0 = (tnum & 31) << 6;
    int cbase = chalf << 8;             // 0 or 256
    int cx = tid & 63;                  // lane
    int q  = tid >> 6;                  // wave
    int c4 = tid & 15;                  // channel quad 0..15 (pass 2)
    int tg = tid >> 4;                  // token group 0..15 (pass 2)
    if (tid < 64) lcodes[tid] = codes[b * T_ + t0 + tid];
    __syncthreads();
    float ax2[4], ad2[4];
#pragma unroll
    for (int j = 0; j < 4; ++j) { ax2[j] = 0.f; ad2[j] = 0.f; }
    for (int c0 = cbase; c0 < cbase + 256; c0 += 64) {
        // pass 1: wave q covers local chans [q*16, q*16+16), float4 along T -> tile[tok][ch]
#pragma unroll
        for (int i = 0; i < 4; ++i) {
            int ch = q * 16 + i * 4 + (cx >> 4);
            int tq = cx & 15;
            float4 v = *(const float4*)(student + (size_t)b * (C_ * T_)
                                        + (size_t)(c0 + ch) * T_ + t0 + tq * 4);
            tile[tq * 4 + 0][ch] = v.x;
            tile[tq * 4 + 1][ch] = v.y;
            tile[tq * 4 + 2][ch] = v.z;
            tile[tq * 4 + 3][ch] = v.w;
        }
        __syncthreads();
        // pass 2: thread (c4, tg) handles tokens tg+16j, channels [c4*4, c4*4+4) of this chunk
#pragma unroll
        for (int j = 0; j < 4; ++j) {
            int tok = tg + j * 16;
            float4 x = *(const float4*)(&tile[tok][c4 * 4]);
            float4 cb = *(const float4*)(codebook + (size_t)lcodes[tok] * C_ + c0 + c4 * 4);
            ax2[j] += x.x*x.x + x.y*x.y + x.z*x.z + x.w*x.w;
            float dx = x.x - cb.x, dy = x.y - cb.y, dz = x.z - cb.z, dw = x.w - cb.w;
            ad2[j] += dx*dx + dy*dy + dz*dz + dw*dw;
            unsigned pk = (unsigned)f2fp8(x.x) | ((unsigned)f2fp8(x.y) << 8)
                        | ((unsigned)f2fp8(x.z) << 16) | ((unsigned)f2fp8(x.w) << 24);
            *(unsigned*)(A8 + (size_t)(b * T_ + t0 + tok) * C_ + c0 + c4 * 4) = pk;
        }
        __syncthreads();
    }
    // reduce over the 16 c4-lanes of each token (consecutive lanes within the wave)
#pragma unroll
    for (int j = 0; j < 4; ++j) {
        float sx = ax2[j], sd = ad2[j];
#pragma unroll
        for (int m = 1; m < 16; m <<= 1) {
            sx += __shfl_xor(sx, m);
            sd += __shfl_xor(sd, m);
        }
        if (c4 == 0) {
            int n = b * T_ + t0 + tg + j * 16;
            atomicAdd(&xnorm[n], sx);
            atomicAdd(&dtg2[n], sd);
        }
    }
}

// ---------------- Kernel 2: R16 exact (best measured: 69.5us, VGPR 40, no spill) ----------------
// grid = 1024 (256 row-strips x 4 col-quarters, XCD-chunked); block = 512 (8 waves, 1x8).
// A LDS: m-pair fraglin [rt][j][lane][16B] (conflict-free, 1 addr reg). B streamed from
// fragment-linear global (coalesced, L2-resident). One barrier total. Fast sqrt epilogue,
// d2-keyed argmin.
__global__ __launch_bounds__(512, 4) void k2_main(
    const unsigned char* __restrict__ A8,
    const unsigned char* __restrict__ B8f,
    const float* __restrict__ xnorm,
    const float* __restrict__ dtg2,
    const float* __restrict__ cbnorm,
    float* __restrict__ s_sum,
    unsigned* __restrict__ minpack)
{
    __shared__ __align__(16) unsigned char aL[32768];      // A: [rt2][j16][lane64][16B]
    __shared__ __align__(16) float cbL[1024];              // cbnorm for this col-quarter
    int tid = threadIdx.x;
    int lane = tid & 63;
    int wc = tid >> 6;                   // 0..7: wave owns cols [wc*32, wc*32+32) of each cc
    int l31 = lane & 31;
    int kh = lane >> 5;

    int orig = blockIdx.x;               // 1024 = 8 XCD x 128
    int swz = (orig & 7) * 128 + (orig >> 3);
    int strip = swz >> 2;                // 0..255
    int cq = swz & 3;                    // col quarter 0..3
    int row0 = strip * 64;
    int cbase = cq * 1024;

    // ---- stage A once, reg->LDS, m-pair fragment-linear layout (R14-verified) ----
#pragma unroll
    for (int i = 0; i < 4; ++i) {
        int li = i * 512 + tid;
        int R = li >> 5, M = li & 31;
        uint4 v = *(const uint4*)(A8 + (size_t)(row0 + R) * C_ + M * 16);
        char* base = (char*)aL + (R >> 5) * 16384 + (M >> 1) * 1024 + (M & 1) * 8;
        *(uint2*)(base + (R & 31) * 16)       = make_uint2(v.x, v.y);   // kh = 0
        *(uint2*)(base + 512 + (R & 31) * 16) = make_uint2(v.z, v.w);   // kh = 1
    }
    // ---- stage cbnorm quarter once ----
    if (tid < 256)
        stage16((const char*)cbnorm + (size_t)cbase * 4 + tid * 16, (char*)cbL + tid * 16);
    __syncthreads();                     // the ONLY barrier

    int myrow0 = row0 + l31, myrow1 = row0 + 32 + l31;
    float xn0 = xnorm[myrow0], xn1 = xnorm[myrow1];
    float dt0 = fsqrt(dtg2[myrow0]), dt1 = fsqrt(dtg2[myrow1]);
    float sv0 = 0.f, sv1 = 0.f;
    unsigned km0 = 0xFFFFFFFFu, km1 = 0xFFFFFFFFu;

    f32x16 acc0, acc1;                   // rt = 0 / 1 (AGPRs)
#pragma unroll
    for (int r = 0; r < 16; ++r) { acc0[r] = 0.f; acc1[r] = 0.f; }

    const char* aBase = (const char*)aL + lane * 16;   // single addr reg; rest is imm offsets
    const unsigned char* gB = B8f + (size_t)(cq * 32 + wc) * 16384 + lane * 8;
    int wlc = wc * 32 + 4 * kh;          // lane's col base within a cc (local)

    for (int cc = 0; cc < 4; ++cc) {
#pragma unroll 4
        for (int j = 0; j < 16; ++j) {
            long bE = *(const long*)(gB + j * 1024);          // B frag m=2j
            long bO = *(const long*)(gB + j * 1024 + 512);    // B frag m=2j+1
            long2v a0 = *(const long2v*)(aBase + j * 1024);           // rt0: {m=2j, m=2j+1}
            long2v a1 = *(const long2v*)(aBase + 16384 + j * 1024);   // rt1
            acc0 = __builtin_amdgcn_mfma_f32_32x32x16_fp8_fp8(bE, a0[0], acc0, 0, 0, 0);
            acc1 = __builtin_amdgcn_mfma_f32_32x32x16_fp8_fp8(bE, a1[0], acc1, 0, 0, 0);
            acc0 = __builtin_amdgcn_mfma_f32_32x32x16_fp8_fp8(bO, a0[1], acc0, 0, 0, 0);
            acc1 = __builtin_amdgcn_mfma_f32_32x32x16_fp8_fp8(bO, a1[1], acc1, 0, 0, 0);
        }
        gB += 8 * 16384;                 // next cc's g-group
        // ---- epilogue burst: fast sqrt; argmin keyed on d2 bits (monotonic == same argmin) ----
        int lc0 = cc * 256 + wlc;
#pragma unroll
        for (int r = 0; r < 16; ++r) {
            int lc = lc0 + (r & 3) + 8 * (r >> 2);
            float cbn = cbL[lc];
            float d2a = fmaxf(fmaf(-2.f, acc0[r], xn0) + cbn, 0.f);
            sv0 += __expf(dt0 - fsqrt(d2a));
            km0 = min(km0, (__float_as_uint(d2a) & 0xFFFFF000u) | (unsigned)(cbase + lc));
            float d2b = fmaxf(fmaf(-2.f, acc1[r], xn1) + cbn, 0.f);
            sv1 += __expf(dt1 - fsqrt(d2b));
            km1 = min(km1, (__float_as_uint(d2b) & 0xFFFFF000u) | (unsigned)(cbase + lc));
            acc0[r] = 0.f; acc1[r] = 0.f;
        }
    }

    // merge k-halves (lane vs lane+32: same student rows, disjoint cb-col quads)
    sv0 += __shfl_xor(sv0, 32);
    sv1 += __shfl_xor(sv1, 32);
    km0 = min(km0, (unsigned)__shfl_xor((int)km0, 32));
    km1 = min(km1, (unsigned)__shfl_xor((int)km1, 32));
    if (lane < 32) {
        atomicAdd(&s_sum[myrow0], sv0);
        atomicMin(&minpack[myrow0], km0);
        atomicAdd(&s_sum[myrow1], sv1);
        atomicMin(&minpack[myrow1], km1);
    }
}

// ---------------- Kernel 3a: per-token CE/accuracy/emb-loss/target-dist reduce ----------------
__global__ __launch_bounds__(256) void k3a(
    const float* __restrict__ s_sum,
    const unsigned* __restrict__ minpack,
    const int* __restrict__ codes,
    const float* __restrict__ dtg2,
    float* __restrict__ accum)
{
    __shared__ float w0[4], w1[4], w2[4], w3[4];
    int tid = threadIdx.x;
    int n = blockIdx.x * 256 + tid;
    float ce = logf(s_sum[n]);           // = d_t + lse(-d) = per-token CE
    unsigned pred = minpack[n] & 0xFFFu; // col id in the low 12 bits
    float ok = (pred == (unsigned)codes[n]) ? 1.f : 0.f;
    float sq = dtg2[n];
    float td = sqrtf(sq);
#pragma unroll
    for (int m = 1; m < 64; m <<= 1) {
        ce += __shfl_xor(ce, m);
        ok += __shfl_xor(ok, m);
        sq += __shfl_xor(sq, m);
        td += __shfl_xor(td, m);
    }
    int lane = tid & 63, w = tid >> 6;
    if (lane == 0) { w0[w] = ce; w1[w] = ok; w2[w] = sq; w3[w] = td; }
    __syncthreads();
    if (tid == 0) {
        atomicAdd(&accum[0], w0[0] + w0[1] + w0[2] + w0[3]);
        atomicAdd(&accum[1], w1[0] + w1[1] + w1[2] + w1[3]);
        atomicAdd(&accum[2], w2[0] + w2[1] + w2[2] + w2[3]);
        atomicAdd(&accum[3], w3[0] + w3[1] + w3[2] + w3[3]);
    }
}

// ---------------- Kernel 3b: finalize 5 outputs ----------------
__global__ void k3b(const float* __restrict__ accum, float* __restrict__ out)
{
    if (threadIdx.x == 0 && blockIdx.x == 0) {
        float ce   = accum[0] / (float)N_TOK;
        float accy = accum[1] / (float)N_TOK;
        float emb  = accum[2] / ((float)N_TOK * (float)C_);
        float td   = accum[3] / (float)N_TOK;
        out[0] = emb + ce;   // total_loss (EMB_W=CE_W=1)
        out[1] = emb;        // emb_to_codebook_loss
        out[2] = ce;         // ce_loss
        out[3] = accy;       // token_accuracy
        out[4] = td;         // emb_to_target_dist
    }
}

extern "C" void kernel_launch(void* const* d_in, const int* in_sizes, int n_in,
                              void* d_out, int out_size, void* d_ws, size_t ws_size,
                              hipStream_t stream)
{
    const float* student  = (const float*)d_in[0];
    const int*   codes    = (const int*)d_in[1];
    const float* codebook = (const float*)d_in[2];
    // d_in[3] distance_matrix is unused by the reference.
    float* out = (float*)d_out;

    char* ws = (char*)d_ws;
    unsigned char* A8     = (unsigned char*)(ws);                  // 8 MiB
    unsigned char* B8f    = (unsigned char*)(ws + 8388608);        // 2 MiB (fragment-linear)
    float* xnorm          = (float*)(ws + 10485760);               // 64 KiB  ─┐
    float* dtg2           = (float*)(ws + 10551296);               // 64 KiB   │ one zero-memset
    float* s_sum          = (float*)(ws + 10616832);               // 64 KiB   │
    float* accum          = (float*)(ws + 10682368);               // 64 B    ─┘
    unsigned* minpack     = (unsigned*)(ws + 10682624);            // 64 KiB (0xFF memset)
    float* cbnorm         = (float*)(ws + 10748160);               // 16 KiB (fully written by k1)

    hipMemsetAsync(ws + 10485760, 0, 196672, stream);              // xnorm+dtg2+s_sum+accum
    hipMemsetAsync(ws + 10682624, 0xFF, 65536, stream);            // minpack

    // merged prep: blocks 0-511 student transpose/stats, 512-1535 codebook conversion
    hipLaunchKernelGGL(k1_all, dim3(1536), dim3(256), 0, stream,
                       student, codes, codebook, A8, B8f, cbnorm, xnorm, dtg2);
    hipLaunchKernelGGL(k2_main, dim3(1024), dim3(512), 0, stream,
                       A8, B8f, xnorm, dtg2, cbnorm, s_sum, minpack);
    hipLaunchKernelGGL(k3a, dim3(64), dim3(256), 0, stream,
                       s_sum, minpack, codes, dtg2, accum);
    hipLaunchKernelGGL(k3b, dim3(1), dim3(64), 0, stream, accum, out);
}

// Round 23
// 96.260 us; speedup vs baseline: 1.1271x; 1.0101x over previous
//
#include <hip/hip_runtime.h>
#include <hip/hip_fp8.h>

#define C_ 512
#define T_ 2048
#define N_TOK 16384
#define K_CB 4096

typedef __attribute__((ext_vector_type(16))) float f32x16;
typedef __attribute__((ext_vector_type(2))) long long2v;

static __device__ __forceinline__ unsigned char f2fp8(float f) {
    __hip_fp8_e4m3 v(f);                 // OCP e4m3, RNE + saturate
    return (unsigned char)v.__x;
}

static __device__ __forceinline__ float fsqrt(float x) {
#if __has_builtin(__builtin_amdgcn_sqrtf)
    return __builtin_amdgcn_sqrtf(x);    // raw v_sqrt_f32 (1-2 ulp), no Newton fixup
#else
    float r; asm volatile("v_sqrt_f32 %0, %1" : "=v"(r) : "v"(x)); return r;
#endif
}

typedef const __attribute__((address_space(1))) void* gas_t;
typedef __attribute__((address_space(3))) void* las_t;
static __device__ __forceinline__ void stage16(const void* g, void* l) {
    __builtin_amdgcn_global_load_lds((gas_t)g, (las_t)l, 16, 0, 0);
}

// ---------------- Kernel 1 (merged): blocks 0-511 = student transpose/stats; 512-1535 = codebook
// Pass-2 vectorized via token-major tile (R22-verified).
__global__ __launch_bounds__(256) void k1_all(
    const float* __restrict__ student,   // (B,C,T) fp32
    const int* __restrict__ codes,       // (B,T) int32
    const float* __restrict__ codebook,  // (K,C) fp32
    unsigned char* __restrict__ A8,      // (N,C) fp8 out
    unsigned char* __restrict__ B8f,     // fragment-linear fp8 codebook out
    float* __restrict__ cbnorm,
    float* __restrict__ xnorm, float* __restrict__ dtg2)
{
    int tid = threadIdx.x;
    if (blockIdx.x >= 512) {
        // ---------------- codebook -> fragment-linear fp8 + row norms ----------------
        int lane = tid & 63;
        int w = tid >> 6;
        int row = (blockIdx.x - 512) * 4 + w;
        const float* src = codebook + (size_t)row * C_ + lane * 8;
        float4 v0 = *(const float4*)(src);
        float4 v1 = *(const float4*)(src + 4);
        float s = v0.x*v0.x + v0.y*v0.y + v0.z*v0.z + v0.w*v0.w
                + v1.x*v1.x + v1.y*v1.y + v1.z*v1.z + v1.w*v1.w;
        unsigned lo = (unsigned)f2fp8(v0.x) | ((unsigned)f2fp8(v0.y) << 8)
                    | ((unsigned)f2fp8(v0.z) << 16) | ((unsigned)f2fp8(v0.w) << 24);
        unsigned hi = (unsigned)f2fp8(v1.x) | ((unsigned)f2fp8(v1.y) << 8)
                    | ((unsigned)f2fp8(v1.z) << 16) | ((unsigned)f2fp8(v1.w) << 24);
        size_t off = (size_t)(row >> 5) * 16384 + (size_t)(lane >> 1) * 512
                   + (size_t)(lane & 1) * 256 + (size_t)(row & 31) * 8;
        *(uint2*)(B8f + off) = make_uint2(lo, hi);
#pragma unroll
        for (int m = 1; m < 64; m <<= 1) s += __shfl_xor(s, m);
        if (lane == 0) cbnorm[row] = s;
        return;
    }
    // ---------------- student transpose (B,C,T)->(N,C) fp8 + per-token partial stats ----------
    __shared__ float tile[64][68];       // [tok][ch]: float4-aligned, 2-way reads
    __shared__ int lcodes[64];
    int tnum  = blockIdx.x >> 1;
    int chalf = blockIdx.x & 1;
    int b  = tnum >> 5;
    int t0 = (tnum & 31) << 6;
    int cbase = chalf << 8;             // 0 or 256
    int cx = tid & 63;                  // lane
    int q  = tid >> 6;                  // wave
    int c4 = tid & 15;                  // channel quad 0..15 (pass 2)
    int tg = tid >> 4;                  // token group 0..15 (pass 2)
    if (tid < 64) lcodes[tid] = codes[b * T_ + t0 + tid];
    __syncthreads();
    float ax2[4], ad2[4];
#pragma unroll
    for (int j = 0; j < 4; ++j) { ax2[j] = 0.f; ad2[j] = 0.f; }
    for (int c0 = cbase; c0 < cbase + 256; c0 += 64) {
        // pass 1: wave q covers local chans [q*16, q*16+16), float4 along T -> tile[tok][ch]
#pragma unroll
        for (int i = 0; i < 4; ++i) {
            int ch = q * 16 + i * 4 + (cx >> 4);
            int tq = cx & 15;
            float4 v = *(const float4*)(student + (size_t)b * (C_ * T_)
                                        + (size_t)(c0 + ch) * T_ + t0 + tq * 4);
            tile[tq * 4 + 0][ch] = v.x;
            tile[tq * 4 + 1][ch] = v.y;
            tile[tq * 4 + 2][ch] = v.z;
            tile[tq * 4 + 3][ch] = v.w;
        }
        __syncthreads();
        // pass 2: thread (c4, tg) handles tokens tg+16j, channels [c4*4, c4*4+4)
#pragma unroll
        for (int j = 0; j < 4; ++j) {
            int tok = tg + j * 16;
            float4 x = *(const float4*)(&tile[tok][c4 * 4]);
            float4 cb = *(const float4*)(codebook + (size_t)lcodes[tok] * C_ + c0 + c4 * 4);
            ax2[j] += x.x*x.x + x.y*x.y + x.z*x.z + x.w*x.w;
            float dx = x.x - cb.x, dy = x.y - cb.y, dz = x.z - cb.z, dw = x.w - cb.w;
            ad2[j] += dx*dx + dy*dy + dz*dz + dw*dw;
            unsigned pk = (unsigned)f2fp8(x.x) | ((unsigned)f2fp8(x.y) << 8)
                        | ((unsigned)f2fp8(x.z) << 16) | ((unsigned)f2fp8(x.w) << 24);
            *(unsigned*)(A8 + (size_t)(b * T_ + t0 + tok) * C_ + c0 + c4 * 4) = pk;
        }
        __syncthreads();
    }
    // reduce over the 16 c4-lanes of each token
#pragma unroll
    for (int j = 0; j < 4; ++j) {
        float sx = ax2[j], sd = ad2[j];
#pragma unroll
        for (int m = 1; m < 16; m <<= 1) {
            sx += __shfl_xor(sx, m);
            sd += __shfl_xor(sd, m);
        }
        if (c4 == 0) {
            int n = b * T_ + t0 + tg + j * 16;
            atomicAdd(&xnorm[n], sx);
            atomicAdd(&dtg2[n], sd);
        }
    }
}

// ---------------- Kernel 2: R16 base + wave-dephased cc schedule ----------------
// grid = 1024 (256 row-strips x 4 col-quarters, XCD-chunked); block = 512 (8 waves, 1x8).
// Each wave starts its cc loop at phase (wc&3): at any instant the 8 waves/SIMD span all 4
// phases, so ~1/4 issue epilogue VALU/trans while 3/4 feed the matrix pipe -- MFMA || VALU
// overlap across waves (m114 mechanism) with ZERO register cost. cc order is arbitrary:
// waves own disjoint columns, A-tile is read-only after staging.
__global__ __launch_bounds__(512, 4) void k2_main(
    const unsigned char* __restrict__ A8,
    const unsigned char* __restrict__ B8f,
    const float* __restrict__ xnorm,
    const float* __restrict__ dtg2,
    const float* __restrict__ cbnorm,
    float* __restrict__ s_sum,
    unsigned* __restrict__ minpack)
{
    __shared__ __align__(16) unsigned char aL[32768];      // A: [rt2][j16][lane64][16B]
    __shared__ __align__(16) float cbL[1024];              // cbnorm for this col-quarter
    int tid = threadIdx.x;
    int lane = tid & 63;
    int wc = tid >> 6;                   // 0..7: wave owns cols [wc*32, wc*32+32) of each cc
    int l31 = lane & 31;
    int kh = lane >> 5;

    int orig = blockIdx.x;               // 1024 = 8 XCD x 128
    int swz = (orig & 7) * 128 + (orig >> 3);
    int strip = swz >> 2;                // 0..255
    int cq = swz & 3;                    // col quarter 0..3
    int row0 = strip * 64;
    int cbase = cq * 1024;

    // ---- stage A once, reg->LDS, m-pair fragment-linear layout (R14-verified) ----
#pragma unroll
    for (int i = 0; i < 4; ++i) {
        int li = i * 512 + tid;
        int R = li >> 5, M = li & 31;
        uint4 v = *(const uint4*)(A8 + (size_t)(row0 + R) * C_ + M * 16);
        char* base = (char*)aL + (R >> 5) * 16384 + (M >> 1) * 1024 + (M & 1) * 8;
        *(uint2*)(base + (R & 31) * 16)       = make_uint2(v.x, v.y);   // kh = 0
        *(uint2*)(base + 512 + (R & 31) * 16) = make_uint2(v.z, v.w);   // kh = 1
    }
    // ---- stage cbnorm quarter once ----
    if (tid < 256)
        stage16((const char*)cbnorm + (size_t)cbase * 4 + tid * 16, (char*)cbL + tid * 16);
    __syncthreads();                     // the ONLY barrier

    int myrow0 = row0 + l31, myrow1 = row0 + 32 + l31;
    float xn0 = xnorm[myrow0], xn1 = xnorm[myrow1];
    float dt0 = fsqrt(dtg2[myrow0]), dt1 = fsqrt(dtg2[myrow1]);
    float sv0 = 0.f, sv1 = 0.f;
    unsigned km0 = 0xFFFFFFFFu, km1 = 0xFFFFFFFFu;

    f32x16 acc0, acc1;                   // rt = 0 / 1 (AGPRs)
#pragma unroll
    for (int r = 0; r < 16; ++r) { acc0[r] = 0.f; acc1[r] = 0.f; }

    const char* aBase = (const char*)aL + lane * 16;   // single addr reg; imm offsets
    const unsigned char* gB0 = B8f + (size_t)(cq * 32 + wc) * 16384 + lane * 8;
    int wlc = wc * 32 + 4 * kh;          // lane's col base within a cc (local)
    int ccStart = wc & 3;                // wave-dependent phase offset (de-phasing)

    for (int i = 0; i < 4; ++i) {
        int cc = (i + ccStart) & 3;
        const unsigned char* gB = gB0 + (size_t)cc * (8 * 16384);
#pragma unroll 4
        for (int j = 0; j < 16; ++j) {
            long bE = *(const long*)(gB + j * 1024);          // B frag m=2j
            long bO = *(const long*)(gB + j * 1024 + 512);    // B frag m=2j+1
            long2v a0 = *(const long2v*)(aBase + j * 1024);           // rt0: {m=2j, m=2j+1}
            long2v a1 = *(const long2v*)(aBase + 16384 + j * 1024);   // rt1
            acc0 = __builtin_amdgcn_mfma_f32_32x32x16_fp8_fp8(bE, a0[0], acc0, 0, 0, 0);
            acc1 = __builtin_amdgcn_mfma_f32_32x32x16_fp8_fp8(bE, a1[0], acc1, 0, 0, 0);
            acc0 = __builtin_amdgcn_mfma_f32_32x32x16_fp8_fp8(bO, a0[1], acc0, 0, 0, 0);
            acc1 = __builtin_amdgcn_mfma_f32_32x32x16_fp8_fp8(bO, a1[1], acc1, 0, 0, 0);
        }
        // ---- epilogue burst: fast sqrt; argmin keyed on d2 bits ----
        int lc0 = cc * 256 + wlc;
#pragma unroll
        for (int r = 0; r < 16; ++r) {
            int lc = lc0 + (r & 3) + 8 * (r >> 2);
            float cbn = cbL[lc];
            float d2a = fmaxf(fmaf(-2.f, acc0[r], xn0) + cbn, 0.f);
            sv0 += __expf(dt0 - fsqrt(d2a));
            km0 = min(km0, (__float_as_uint(d2a) & 0xFFFFF000u) | (unsigned)(cbase + lc));
            float d2b = fmaxf(fmaf(-2.f, acc1[r], xn1) + cbn, 0.f);
            sv1 += __expf(dt1 - fsqrt(d2b));
            km1 = min(km1, (__float_as_uint(d2b) & 0xFFFFF000u) | (unsigned)(cbase + lc));
            acc0[r] = 0.f; acc1[r] = 0.f;
        }
    }

    // merge k-halves (lane vs lane+32: same student rows, disjoint cb-col quads)
    sv0 += __shfl_xor(sv0, 32);
    sv1 += __shfl_xor(sv1, 32);
    km0 = min(km0, (unsigned)__shfl_xor((int)km0, 32));
    km1 = min(km1, (unsigned)__shfl_xor((int)km1, 32));
    if (lane < 32) {
        atomicAdd(&s_sum[myrow0], sv0);
        atomicMin(&minpack[myrow0], km0);
        atomicAdd(&s_sum[myrow1], sv1);
        atomicMin(&minpack[myrow1], km1);
    }
}

// ---------------- Kernel 3a: per-token CE/accuracy/emb-loss/target-dist reduce ----------------
__global__ __launch_bounds__(256) void k3a(
    const float* __restrict__ s_sum,
    const unsigned* __restrict__ minpack,
    const int* __restrict__ codes,
    const float* __restrict__ dtg2,
    float* __restrict__ accum)
{
    __shared__ float w0[4], w1[4], w2[4], w3[4];
    int tid = threadIdx.x;
    int n = blockIdx.x * 256 + tid;
    float ce = logf(s_sum[n]);           // = d_t + lse(-d) = per-token CE
    unsigned pred = minpack[n] & 0xFFFu; // col id in the low 12 bits
    float ok = (pred == (unsigned)codes[n]) ? 1.f : 0.f;
    float sq = dtg2[n];
    float td = sqrtf(sq);
#pragma unroll
    for (int m = 1; m < 64; m <<= 1) {
        ce += __shfl_xor(ce, m);
        ok += __shfl_xor(ok, m);
        sq += __shfl_xor(sq, m);
        td += __shfl_xor(td, m);
    }
    int lane = tid & 63, w = tid >> 6;
    if (lane == 0) { w0[w] = ce; w1[w] = ok; w2[w] = sq; w3[w] = td; }
    __syncthreads();
    if (tid == 0) {
        atomicAdd(&accum[0], w0[0] + w0[1] + w0[2] + w0[3]);
        atomicAdd(&accum[1], w1[0] + w1[1] + w1[2] + w1[3]);
        atomicAdd(&accum[2], w2[0] + w2[1] + w2[2] + w2[3]);
        atomicAdd(&accum[3], w3[0] + w3[1] + w3[2] + w3[3]);
    }
}

// ---------------- Kernel 3b: finalize 5 outputs ----------------
__global__ void k3b(const float* __restrict__ accum, float* __restrict__ out)
{
    if (threadIdx.x == 0 && blockIdx.x == 0) {
        float ce   = accum[0] / (float)N_TOK;
        float accy = accum[1] / (float)N_TOK;
        float emb  = accum[2] / ((float)N_TOK * (float)C_);
        float td   = accum[3] / (float)N_TOK;
        out[0] = emb + ce;   // total_loss (EMB_W=CE_W=1)
        out[1] = emb;        // emb_to_codebook_loss
        out[2] = ce;         // ce_loss
        out[3] = accy;       // token_accuracy
        out[4] = td;         // emb_to_target_dist
    }
}

extern "C" void kernel_launch(void* const* d_in, const int* in_sizes, int n_in,
                              void* d_out, int out_size, void* d_ws, size_t ws_size,
                              hipStream_t stream)
{
    const float* student  = (const float*)d_in[0];
    const int*   codes    = (const int*)d_in[1];
    const float* codebook = (const float*)d_in[2];
    // d_in[3] distance_matrix is unused by the reference.
    float* out = (float*)d_out;

    char* ws = (char*)d_ws;
    unsigned char* A8     = (unsigned char*)(ws);                  // 8 MiB
    unsigned char* B8f    = (unsigned char*)(ws + 8388608);        // 2 MiB (fragment-linear)
    float* xnorm          = (float*)(ws + 10485760);               // 64 KiB  ─┐
    float* dtg2           = (float*)(ws + 10551296);               // 64 KiB   │ one zero-memset
    float* s_sum          = (float*)(ws + 10616832);               // 64 KiB   │
    float* accum          = (float*)(ws + 10682368);               // 64 B    ─┘
    unsigned* minpack     = (unsigned*)(ws + 10682624);            // 64 KiB (0xFF memset)
    float* cbnorm         = (float*)(ws + 10748160);               // 16 KiB (fully written by k1)

    hipMemsetAsync(ws + 10485760, 0, 196672, stream);              // xnorm+dtg2+s_sum+accum
    hipMemsetAsync(ws + 10682624, 0xFF, 65536, stream);            // minpack

    // merged prep: blocks 0-511 student transpose/stats, 512-1535 codebook conversion
    hipLaunchKernelGGL(k1_all, dim3(1536), dim3(256), 0, stream,
                       student, codes, codebook, A8, B8f, cbnorm, xnorm, dtg2);
    hipLaunchKernelGGL(k2_main, dim3(1024), dim3(512), 0, stream,
                       A8, B8f, xnorm, dtg2, cbnorm, s_sum, minpack);
    hipLaunchKernelGGL(k3a, dim3(64), dim3(256), 0, stream,
                       s_sum, minpack, codes, dtg2, accum);
    hipLaunchKernelGGL(k3b, dim3(1), dim3(64), 0, stream, accum, out);
}

// Round 24
// 79.706 us; speedup vs baseline: 1.3612x; 1.2077x over previous
//
#include <hip/hip_runtime.h>
#include <hip/hip_fp8.h>

#define C_ 512
#define T_ 2048
#define N_TOK 16384
#define K_CB 4096

typedef __attribute__((ext_vector_type(16))) float f32x16;
typedef __attribute__((ext_vector_type(8))) int i32x8;

static __device__ __forceinline__ unsigned char f2fp8(float f) {
    __hip_fp8_e4m3 v(f);                 // OCP e4m3, RNE + saturate
    return (unsigned char)v.__x;
}

static __device__ __forceinline__ float fsqrt(float x) {
#if __has_builtin(__builtin_amdgcn_sqrtf)
    return __builtin_amdgcn_sqrtf(x);    // raw v_sqrt_f32 (1-2 ulp), no Newton fixup
#else
    float r; asm volatile("v_sqrt_f32 %0, %1" : "=v"(r) : "v"(x)); return r;
#endif
}

static __device__ __forceinline__ i32x8 mk8(uint4 lo, uint4 hi) {
    i32x8 r;
    r[0] = (int)lo.x; r[1] = (int)lo.y; r[2] = (int)lo.z; r[3] = (int)lo.w;
    r[4] = (int)hi.x; r[5] = (int)hi.y; r[6] = (int)hi.z; r[7] = (int)hi.w;
    return r;
}

typedef const __attribute__((address_space(1))) void* gas_t;
typedef __attribute__((address_space(3))) void* las_t;
static __device__ __forceinline__ void stage16(const void* g, void* l) {
    __builtin_amdgcn_global_load_lds((gas_t)g, (las_t)l, 16, 0, 0);
}

// ---------------- Kernel 1 (merged): blocks 0-511 = student transpose/stats; 512-1535 = codebook
// B8f layout (MX 32B-granule fragment-linear): addr(row, k) = (row>>5)*16384 + (k>>6)*2048
// + ((k>>5)&1)*1024 + (row&31)*32 + (k&31)  -> a wave's 32x64 fragment is lane-contiguous 32B.
__global__ __launch_bounds__(256) void k1_all(
    const float* __restrict__ student,   // (B,C,T) fp32
    const int* __restrict__ codes,       // (B,T) int32
    const float* __restrict__ codebook,  // (K,C) fp32
    unsigned char* __restrict__ A8,      // (N,C) fp8 out
    unsigned char* __restrict__ B8f,     // fragment-linear fp8 codebook out
    float* __restrict__ cbnorm,
    float* __restrict__ xnorm, float* __restrict__ dtg2)
{
    int tid = threadIdx.x;
    if (blockIdx.x >= 512) {
        // ---------------- codebook -> fragment-linear fp8 + row norms ----------------
        int lane = tid & 63;
        int w = tid >> 6;
        int row = (blockIdx.x - 512) * 4 + w;
        const float* src = codebook + (size_t)row * C_ + lane * 8;
        float4 v0 = *(const float4*)(src);
        float4 v1 = *(const float4*)(src + 4);
        float s = v0.x*v0.x + v0.y*v0.y + v0.z*v0.z + v0.w*v0.w
                + v1.x*v1.x + v1.y*v1.y + v1.z*v1.z + v1.w*v1.w;
        unsigned lo = (unsigned)f2fp8(v0.x) | ((unsigned)f2fp8(v0.y) << 8)
                    | ((unsigned)f2fp8(v0.z) << 16) | ((unsigned)f2fp8(v0.w) << 24);
        unsigned hi = (unsigned)f2fp8(v1.x) | ((unsigned)f2fp8(v1.y) << 8)
                    | ((unsigned)f2fp8(v1.z) << 16) | ((unsigned)f2fp8(v1.w) << 24);
        // lane covers k-bytes [lane*8, lane*8+8)
        size_t off = (size_t)(row >> 5) * 16384 + (size_t)(lane >> 3) * 2048
                   + (size_t)((lane >> 2) & 1) * 1024 + (size_t)(row & 31) * 32
                   + (size_t)(lane & 3) * 8;
        *(uint2*)(B8f + off) = make_uint2(lo, hi);
#pragma unroll
        for (int m = 1; m < 64; m <<= 1) s += __shfl_xor(s, m);
        if (lane == 0) cbnorm[row] = s;
        return;
    }
    // ---------------- student transpose (B,C,T)->(N,C) fp8 + per-token partial stats ----------
    __shared__ float tile[64][68];       // [tok][ch]: float4-aligned, 2-way reads
    __shared__ int lcodes[64];
    int tnum  = blockIdx.x >> 1;
    int chalf = blockIdx.x & 1;
    int b  = tnum >> 5;
    int t0 = (tnum & 31) << 6;
    int cbase = chalf << 8;             // 0 or 256
    int cx = tid & 63;                  // lane
    int q  = tid >> 6;                  // wave
    int c4 = tid & 15;                  // channel quad 0..15 (pass 2)
    int tg = tid >> 4;                  // token group 0..15 (pass 2)
    if (tid < 64) lcodes[tid] = codes[b * T_ + t0 + tid];
    __syncthreads();
    float ax2[4], ad2[4];
#pragma unroll
    for (int j = 0; j < 4; ++j) { ax2[j] = 0.f; ad2[j] = 0.f; }
    for (int c0 = cbase; c0 < cbase + 256; c0 += 64) {
        // pass 1: wave q covers local chans [q*16, q*16+16), float4 along T -> tile[tok][ch]
#pragma unroll
        for (int i = 0; i < 4; ++i) {
            int ch = q * 16 + i * 4 + (cx >> 4);
            int tq = cx & 15;
            float4 v = *(const float4*)(student + (size_t)b * (C_ * T_)
                                        + (size_t)(c0 + ch) * T_ + t0 + tq * 4);
            tile[tq * 4 + 0][ch] = v.x;
            tile[tq * 4 + 1][ch] = v.y;
            tile[tq * 4 + 2][ch] = v.z;
            tile[tq * 4 + 3][ch] = v.w;
        }
        __syncthreads();
        // pass 2: thread (c4, tg) handles tokens tg+16j, channels [c4*4, c4*4+4)
#pragma unroll
        for (int j = 0; j < 4; ++j) {
            int tok = tg + j * 16;
            float4 x = *(const float4*)(&tile[tok][c4 * 4]);
            float4 cb = *(const float4*)(codebook + (size_t)lcodes[tok] * C_ + c0 + c4 * 4);
            ax2[j] += x.x*x.x + x.y*x.y + x.z*x.z + x.w*x.w;
            float dx = x.x - cb.x, dy = x.y - cb.y, dz = x.z - cb.z, dw = x.w - cb.w;
            ad2[j] += dx*dx + dy*dy + dz*dz + dw*dw;
            unsigned pk = (unsigned)f2fp8(x.x) | ((unsigned)f2fp8(x.y) << 8)
                        | ((unsigned)f2fp8(x.z) << 16) | ((unsigned)f2fp8(x.w) << 24);
            *(unsigned*)(A8 + (size_t)(b * T_ + t0 + tok) * C_ + c0 + c4 * 4) = pk;
        }
        __syncthreads();
    }
    // reduce over the 16 c4-lanes of each token
#pragma unroll
    for (int j = 0; j < 4; ++j) {
        float sx = ax2[j], sd = ad2[j];
#pragma unroll
        for (int m = 1; m < 16; m <<= 1) {
            sx += __shfl_xor(sx, m);
            sd += __shfl_xor(sd, m);
        }
        if (c4 == 0) {
            int n = b * T_ + t0 + tg + j * 16;
            atomicAdd(&xnorm[n], sx);
            atomicAdd(&dtg2[n], sd);
        }
    }
}

// ---------------- Kernel 2: MX-scaled fp8 32x32x64 MFMA (2x rate, unit scales) ----------------
// grid = 1024 (256 row-strips x 4 col-quarters, XCD-chunked); block = 512 (8 waves, 1x8).
// A LDS: [rt2][j'8][half2][lane64][16B] -- two conflict-free stride-16 ds_read_b128 per
// fragment (32B/lane). B from fragment-linear global (lane-contiguous 32B, L2-resident).
// mfma_scale_f32_32x32x64_f8f6f4 with E8M0 scale 127 (=1.0) both sides = exact fp8 GEMM at
// 2x rate, 1/4 the MFMA instructions. C/D layout shape-determined -> epilogue unchanged.
__global__ __launch_bounds__(512, 4) void k2_main(
    const unsigned char* __restrict__ A8,
    const unsigned char* __restrict__ B8f,
    const float* __restrict__ xnorm,
    const float* __restrict__ dtg2,
    const float* __restrict__ cbnorm,
    float* __restrict__ s_sum,
    unsigned* __restrict__ minpack)
{
    __shared__ __align__(16) unsigned char aL[32768];      // A: [rt2][j'8][half2][lane64][16B]
    __shared__ __align__(16) float cbL[1024];              // cbnorm for this col-quarter
    int tid = threadIdx.x;
    int lane = tid & 63;
    int wc = tid >> 6;                   // 0..7: wave owns cols [wc*32, wc*32+32) of each cc
    int l31 = lane & 31;
    int kh = lane >> 5;

    int orig = blockIdx.x;               // 1024 = 8 XCD x 128
    int swz = (orig & 7) * 128 + (orig >> 3);
    int strip = swz >> 2;                // 0..255
    int cq = swz & 3;                    // col quarter 0..3
    int row0 = strip * 64;
    int cbase = cq * 1024;

    // ---- stage A once: thread owns row (tid>>3), 64B k-chunk (tid&7) = granules M=(tid&7)*4+i
    // dest = (R>>5)*16384 + j'(=tid&7)*2048 + (i&1)*1024 + ((i>>1)*32 + (R&31))*16
    {
        int R = tid >> 3;
        const unsigned char* srcA = A8 + (size_t)(row0 + R) * C_ + (tid & 7) * 64;
        char* dA = (char*)aL + (R >> 5) * 16384 + (tid & 7) * 2048 + (R & 31) * 16;
#pragma unroll
        for (int i = 0; i < 4; ++i) {
            uint4 v = *(const uint4*)(srcA + i * 16);
            *(uint4*)(dA + (i & 1) * 1024 + (i >> 1) * 512) = v;
        }
    }
    // ---- stage cbnorm quarter once ----
    if (tid < 256)
        stage16((const char*)cbnorm + (size_t)cbase * 4 + tid * 16, (char*)cbL + tid * 16);
    __syncthreads();                     // the ONLY barrier

    int myrow0 = row0 + l31, myrow1 = row0 + 32 + l31;
    float xn0 = xnorm[myrow0], xn1 = xnorm[myrow1];
    float dt0 = fsqrt(dtg2[myrow0]), dt1 = fsqrt(dtg2[myrow1]);
    float sv0 = 0.f, sv1 = 0.f;
    unsigned km0 = 0xFFFFFFFFu, km1 = 0xFFFFFFFFu;

    f32x16 acc0, acc1;                   // rt = 0 / 1 (AGPRs)
#pragma unroll
    for (int r = 0; r < 16; ++r) { acc0[r] = 0.f; acc1[r] = 0.f; }

    const char* aBase = (const char*)aL + lane * 16;   // single addr reg; imm offsets
    const unsigned char* gB = B8f + (size_t)(cq * 32 + wc) * 16384 + kh * 1024 + l31 * 32;
    int wlc = wc * 32 + 4 * kh;          // lane's col base within a cc (local)

    for (int cc = 0; cc < 4; ++cc) {
#pragma unroll 2
        for (int jp = 0; jp < 8; ++jp) {
            uint4 bl  = *(const uint4*)(gB + jp * 2048);
            uint4 bh  = *(const uint4*)(gB + jp * 2048 + 16);
            uint4 al0 = *(const uint4*)(aBase + jp * 2048);
            uint4 ah0 = *(const uint4*)(aBase + jp * 2048 + 1024);
            uint4 al1 = *(const uint4*)(aBase + 16384 + jp * 2048);
            uint4 ah1 = *(const uint4*)(aBase + 16384 + jp * 2048 + 1024);
            i32x8 bV = mk8(bl, bh);
            acc0 = __builtin_amdgcn_mfma_scale_f32_32x32x64_f8f6f4(
                       bV, mk8(al0, ah0), acc0, 0, 0, 0, 127, 0, 127);
            acc1 = __builtin_amdgcn_mfma_scale_f32_32x32x64_f8f6f4(
                       bV, mk8(al1, ah1), acc1, 0, 0, 0, 127, 0, 127);
        }
        gB += 8 * 16384;                 // next cc's g-group
        // ---- epilogue burst: fast sqrt; argmin keyed on d2 bits ----
        int lc0 = cc * 256 + wlc;
#pragma unroll
        for (int r = 0; r < 16; ++r) {
            int lc = lc0 + (r & 3) + 8 * (r >> 2);
            float cbn = cbL[lc];
            float d2a = fmaxf(fmaf(-2.f, acc0[r], xn0) + cbn, 0.f);
            sv0 += __expf(dt0 - fsqrt(d2a));
            km0 = min(km0, (__float_as_uint(d2a) & 0xFFFFF000u) | (unsigned)(cbase + lc));
            float d2b = fmaxf(fmaf(-2.f, acc1[r], xn1) + cbn, 0.f);
            sv1 += __expf(dt1 - fsqrt(d2b));
            km1 = min(km1, (__float_as_uint(d2b) & 0xFFFFF000u) | (unsigned)(cbase + lc));
            acc0[r] = 0.f; acc1[r] = 0.f;
        }
    }

    // merge k-halves (lane vs lane+32: same student rows, disjoint cb-col quads)
    sv0 += __shfl_xor(sv0, 32);
    sv1 += __shfl_xor(sv1, 32);
    km0 = min(km0, (unsigned)__shfl_xor((int)km0, 32));
    km1 = min(km1, (unsigned)__shfl_xor((int)km1, 32));
    if (lane < 32) {
        atomicAdd(&s_sum[myrow0], sv0);
        atomicMin(&minpack[myrow0], km0);
        atomicAdd(&s_sum[myrow1], sv1);
        atomicMin(&minpack[myrow1], km1);
    }
}

// ---------------- Kernel 3a: per-token CE/accuracy/emb-loss/target-dist reduce ----------------
__global__ __launch_bounds__(256) void k3a(
    const float* __restrict__ s_sum,
    const unsigned* __restrict__ minpack,
    const int* __restrict__ codes,
    const float* __restrict__ dtg2,
    float* __restrict__ accum)
{
    __shared__ float w0[4], w1[4], w2[4], w3[4];
    int tid = threadIdx.x;
    int n = blockIdx.x * 256 + tid;
    float ce = logf(s_sum[n]);           // = d_t + lse(-d) = per-token CE
    unsigned pred = minpack[n] & 0xFFFu; // col id in the low 12 bits
    float ok = (pred == (unsigned)codes[n]) ? 1.f : 0.f;
    float sq = dtg2[n];
    float td = sqrtf(sq);
#pragma unroll
    for (int m = 1; m < 64; m <<= 1) {
        ce += __shfl_xor(ce, m);
        ok += __shfl_xor(ok, m);
        sq += __shfl_xor(sq, m);
        td += __shfl_xor(td, m);
    }
    int lane = tid & 63, w = tid >> 6;
    if (lane == 0) { w0[w] = ce; w1[w] = ok; w2[w] = sq; w3[w] = td; }
    __syncthreads();
    if (tid == 0) {
        atomicAdd(&accum[0], w0[0] + w0[1] + w0[2] + w0[3]);
        atomicAdd(&accum[1], w1[0] + w1[1] + w1[2] + w1[3]);
        atomicAdd(&accum[2], w2[0] + w2[1] + w2[2] + w2[3]);
        atomicAdd(&accum[3], w3[0] + w3[1] + w3[2] + w3[3]);
    }
}

// ---------------- Kernel 3b: finalize 5 outputs ----------------
__global__ void k3b(const float* __restrict__ accum, float* __restrict__ out)
{
    if (threadIdx.x == 0 && blockIdx.x == 0) {
        float ce   = accum[0] / (float)N_TOK;
        float accy = accum[1] / (float)N_TOK;
        float emb  = accum[2] / ((float)N_TOK * (float)C_);
        float td   = accum[3] / (float)N_TOK;
        out[0] = emb + ce;   // total_loss (EMB_W=CE_W=1)
        out[1] = emb;        // emb_to_codebook_loss
        out[2] = ce;         // ce_loss
        out[3] = accy;       // token_accuracy
        out[4] = td;         // emb_to_target_dist
    }
}

extern "C" void kernel_launch(void* const* d_in, const int* in_sizes, int n_in,
                              void* d_out, int out_size, void* d_ws, size_t ws_size,
                              hipStream_t stream)
{
    const float* student  = (const float*)d_in[0];
    const int*   codes    = (const int*)d_in[1];
    const float* codebook = (const float*)d_in[2];
    // d_in[3] distance_matrix is unused by the reference.
    float* out = (float*)d_out;

    char* ws = (char*)d_ws;
    unsigned char* A8     = (unsigned char*)(ws);                  // 8 MiB
    unsigned char* B8f    = (unsigned char*)(ws + 8388608);        // 2 MiB (fragment-linear)
    float* xnorm          = (float*)(ws + 10485760);               // 64 KiB  ─┐
    float* dtg2           = (float*)(ws + 10551296);               // 64 KiB   │ one zero-memset
    float* s_sum          = (float*)(ws + 10616832);               // 64 KiB   │
    float* accum          = (float*)(ws + 10682368);               // 64 B    ─┘
    unsigned* minpack     = (unsigned*)(ws + 10682624);            // 64 KiB (0xFF memset)
    float* cbnorm         = (float*)(ws + 10748160);               // 16 KiB (fully written by k1)

    hipMemsetAsync(ws + 10485760, 0, 196672, stream);              // xnorm+dtg2+s_sum+accum
    hipMemsetAsync(ws + 10682624, 0xFF, 65536, stream);            // minpack

    // merged prep: blocks 0-511 student transpose/stats, 512-1535 codebook conversion
    hipLaunchKernelGGL(k1_all, dim3(1536), dim3(256), 0, stream,
                       student, codes, codebook, A8, B8f, cbnorm, xnorm, dtg2);
    hipLaunchKernelGGL(k2_main, dim3(1024), dim3(512), 0, stream,
                       A8, B8f, xnorm, dtg2, cbnorm, s_sum, minpack);
    hipLaunchKernelGGL(k3a, dim3(64), dim3(256), 0, stream,
                       s_sum, minpack, codes, dtg2, accum);
    hipLaunchKernelGGL(k3b, dim3(1), dim3(64), 0, stream, accum, out);
}